// Round 18
// baseline (86.833 us; speedup 1.0000x reference)
//
#include <hip/hip_runtime.h>

#define N     384
#define BSZ   192
#define NM1   383
#define D     1024
#define DELTA 0.1f
#define NT    24                    // 16-row panels / tiles per dim
#define NTILES (NT * (NT + 1) / 2)  // 300 upper-tri tiles
#define PANEL 16384                 // halfs per panel: 16 rows * 1024
#define SPIN_TICKS 5000ULL          // 50.70 us (calibrated R10: 6000 -> 60.84)

typedef __attribute__((ext_vector_type(8))) short bf16x8;
typedef __attribute__((ext_vector_type(8))) unsigned short u16x8;
typedef __attribute__((ext_vector_type(4))) float f32x4;

__device__ __forceinline__ void tail_spin() {
    unsigned long long t0 = __builtin_amdgcn_s_memrealtime();
    while (__builtin_amdgcn_s_memrealtime() - t0 < SPIN_TICKS)
        __builtin_amdgcn_s_sleep(2);
}

__device__ __forceinline__ const float* feat_row(const float* feats, int i) {
    // features laid out [192][2][1024]; logical row i of the [384,1024] concat
    int b = (i < BSZ) ? i : (i - BSZ);
    int s = (i < BSZ) ? 0 : 1;
    return feats + (size_t)(b * 2 + s) * D;
}

__device__ __forceinline__ unsigned short f2bf(float x) {  // RNE f32->bf16
    unsigned u = __builtin_bit_cast(unsigned, x);
    u = (u + 0x7FFFu + ((u >> 16) & 1u)) >> 16;
    return (unsigned short)u;
}
__device__ __forceinline__ float bf2f(unsigned short h) {
    unsigned u = ((unsigned)h) << 16;
    return __builtin_bit_cast(float, u);
}

// Panel-cooperative cvt (unchanged from R17).
__global__ __launch_bounds__(256) void k_cvt(const float* __restrict__ feats,
                                             unsigned short* __restrict__ Ht,
                                             unsigned short* __restrict__ Lt,
                                             float* __restrict__ sq) {
    const int p = blockIdx.x, tid = threadIdx.x;
    const int r16 = tid & 15;
    const float* fr = feat_row(feats, p * 16 + r16);
    float p2 = 0.f;
#pragma unroll
    for (int w = 0; w < 8; ++w) {
        const int k8 = w * 16 + (tid >> 4);
        const float4 va = *(const float4*)(fr + k8 * 8);
        const float4 vb = *(const float4*)(fr + k8 * 8 + 4);
        p2 = fmaf(va.x, va.x, p2); p2 = fmaf(va.y, va.y, p2);
        p2 = fmaf(va.z, va.z, p2); p2 = fmaf(va.w, va.w, p2);
        p2 = fmaf(vb.x, vb.x, p2); p2 = fmaf(vb.y, vb.y, p2);
        p2 = fmaf(vb.z, vb.z, p2); p2 = fmaf(vb.w, vb.w, p2);
        u16x8 hv, lv;
        hv[0] = f2bf(va.x); lv[0] = f2bf(va.x - bf2f(hv[0]));
        hv[1] = f2bf(va.y); lv[1] = f2bf(va.y - bf2f(hv[1]));
        hv[2] = f2bf(va.z); lv[2] = f2bf(va.z - bf2f(hv[2]));
        hv[3] = f2bf(va.w); lv[3] = f2bf(va.w - bf2f(hv[3]));
        hv[4] = f2bf(vb.x); lv[4] = f2bf(vb.x - bf2f(hv[4]));
        hv[5] = f2bf(vb.y); lv[5] = f2bf(vb.y - bf2f(hv[5]));
        hv[6] = f2bf(vb.z); lv[6] = f2bf(vb.z - bf2f(hv[6]));
        hv[7] = f2bf(vb.w); lv[7] = f2bf(vb.w - bf2f(hv[7]));
        const size_t o = (size_t)p * PANEL + (size_t)k8 * 128 + r16 * 8;
        *(u16x8*)(Ht + o) = hv;
        *(u16x8*)(Lt + o) = lv;
    }
    __shared__ float red[16][17];
    red[tid >> 4][r16] = p2;
    __syncthreads();
    if (tid < 16) {
        float s = 0.f;
#pragma unroll
        for (int g = 0; g < 16; ++g) s += red[g][tid];
        sq[p * 16 + tid] = s;
    }
}

// Gram via MFMA on fragment-major H/L (unchanged; measured ~2.9us in R11).
__global__ __launch_bounds__(256) void k_gram(const unsigned short* __restrict__ Ht,
                                              const unsigned short* __restrict__ Lt,
                                              const float* __restrict__ sq,
                                              float* __restrict__ z) {
    int t = blockIdx.x, bi = 0;
    while (t >= NT - bi) { t -= NT - bi; ++bi; }
    const int bj = bi + t;
    const bool diag = (bi == bj);

    const int tid = threadIdx.x;
    const int lane = tid & 63, wv = tid >> 6;

    const size_t aBase = (size_t)bi * PANEL + (size_t)(wv * 32 + (lane >> 4)) * 128
                       + (size_t)(lane & 15) * 8;
    const size_t bBase = (size_t)bj * PANEL + (size_t)(wv * 32 + (lane >> 4)) * 128
                       + (size_t)(lane & 15) * 8;

    f32x4 aHH = {0.f,0.f,0.f,0.f}, aHL = {0.f,0.f,0.f,0.f}, aLH = {0.f,0.f,0.f,0.f};
#pragma unroll
    for (int s = 0; s < 8; ++s) {
        bf16x8 aH = *(const bf16x8*)(Ht + aBase + s * 512);
        bf16x8 aL = *(const bf16x8*)(Lt + aBase + s * 512);
        bf16x8 bH = *(const bf16x8*)(Ht + bBase + s * 512);
        bf16x8 bL = *(const bf16x8*)(Lt + bBase + s * 512);
        aHH = __builtin_amdgcn_mfma_f32_16x16x32_bf16(aH, bH, aHH, 0, 0, 0);
        aHL = __builtin_amdgcn_mfma_f32_16x16x32_bf16(aH, bL, aHL, 0, 0, 0);
        aLH = __builtin_amdgcn_mfma_f32_16x16x32_bf16(aL, bH, aLH, 0, 0, 0);
    }
    __shared__ f32x4 red[4][64];
    red[wv][lane] = aHH + aHL + aLH;
    __syncthreads();
    const int ls = tid & 63, r = tid >> 6;
    float g = red[0][ls][r] + red[1][ls][r] + red[2][ls][r] + red[3][ls][r];
    // C/D layout (verified): col = lane&15, row = (lane>>4)*4 + reg
    const int jj = bj * 16 + (ls & 15);
    const int ii = bi * 16 + ((ls >> 4) << 2) + r;
    if (ii != jj && (!diag || ii < jj)) {
        float sd = fmaxf(sq[ii] + sq[jj] - 2.f * g, 0.f);
        float v  = sqrtf(sd);
        z[ii * NM1 + (jj < ii ? jj : jj - 1)] = v;
        z[jj * NM1 + (ii < jj ? ii : ii - 1)] = v;
    }
}

// Full k_main (unchanged from R17).
__global__ __launch_bounds__(512) void k_main(const float* __restrict__ z,
                                              const int* __restrict__ labels,
                                              float* __restrict__ partial) {
    const int i = blockIdx.x, tid = threadIdx.x;
    const int lane = tid & 63, wv = tid >> 6;
    __shared__ float zbuf[NM1];
    __shared__ unsigned char yrow[NM1];
    __shared__ int cnt[64], startv[64], cur[64];
    __shared__ float rankd[64];
    __shared__ float2 zr[N];
    __shared__ unsigned grs[N];

    if (tid < 64) cnt[tid] = 0;
    for (int k = tid; k < NM1; k += 512) zbuf[k] = z[i * NM1 + k];
    __syncthreads();
    const int li = labels[(i < BSZ) ? i : (i - BSZ)];
    for (int k = tid; k < NM1; k += 512) {
        int col = k + (k >= i ? 1 : 0);
        int ya  = abs(li - labels[(col < BSZ) ? col : (col - BSZ)]);
        yrow[k] = (unsigned char)ya;
        atomicAdd(&cnt[ya], 1);
    }
    __syncthreads();
    if (tid < 64) {
        const int c  = cnt[tid];
        const int nz = (c > 0) ? 1 : 0;
        int sc = c, sn = nz;
#pragma unroll
        for (int d = 1; d < 64; d <<= 1) {
            int tc = __shfl_up(sc, d);
            int tn = __shfl_up(sn, d);
            if (tid >= d) { sc += tc; sn += tn; }
        }
        startv[tid] = sc - c;
        cur[tid]    = sc - c;
        rankd[tid]  = (float)(sn - nz) * DELTA;
    }
    __syncthreads();
    for (int k = tid; k < NM1; k += 512) {
        int ya  = yrow[k];
        int pos = atomicAdd(&cur[ya], 1);
        zr[pos]  = make_float2(zbuf[k], rankd[ya]);
        grs[pos] = (unsigned)startv[ya] | ((unsigned)(startv[ya] + cnt[ya]) << 9);
    }
    if (tid == 0) { zr[NM1] = make_float2(0.f, 0.f); grs[NM1] = 0u; }
    __syncthreads();

    float2 S[6];
#pragma unroll
    for (int s = 0; s < 6; ++s) S[s] = zr[lane + 64 * s];

    const int j0 = wv * 48;
    const int j1 = (j0 + 48 < NM1) ? j0 + 48 : NM1;

    float a0[6] = {0,0,0,0,0,0}, a1[6] = {0,0,0,0,0,0};
    int j = j0;
    for (; j + 2 <= j1; j += 2) {
        const float4 q = *(const float4*)&zr[j];
#pragma unroll
        for (int s = 0; s < 6; ++s) {
            float tA = fabsf(S[s].x - q.x) - fabsf(S[s].y - q.y);
            a0[s] = fmaf(tA, tA, a0[s]);
            float tB = fabsf(S[s].x - q.z) - fabsf(S[s].y - q.w);
            a1[s] = fmaf(tB, tB, a1[s]);
        }
    }
    if (j < j1) {
        const float2 q = zr[j];
#pragma unroll
        for (int s = 0; s < 6; ++s) {
            float tA = fabsf(S[s].x - q.x) - fabsf(S[s].y - q.y);
            a0[s] = fmaf(tA, tA, a0[s]);
        }
    }
    float sum = 0.f;
#pragma unroll
    for (int s = 0; s < 6; ++s) sum += a0[s] + a1[s];

    if (tid < NM1) {
        float2 e = zr[tid];
        float d = e.x - e.y;
        sum = fmaf(-d, d, sum);
    }

    if (tid < NM1) {
        const float    zj = zr[tid].x;
        const unsigned g  = grs[tid];
        const int lo = g & 0x1FF;
        const int hi = (g >> 9) & 0x1FF;
        float cs = 0.f;
        for (int k = lo; k < hi; ++k) {
            float a = fabsf(zr[k].x - zj);
            cs += a * __builtin_amdgcn_rcpf(1.f + __expf(DELTA - a)) - a * a;
        }
        sum += cs;
    }

#pragma unroll
    for (int off = 32; off; off >>= 1) sum += __shfl_xor(sum, off);
    __shared__ float part[8];
    if (lane == 0) part[wv] = sum;
    __syncthreads();
    if (tid == 0) {
        float ps = 0.f;
#pragma unroll
        for (int w = 0; w < 8; ++w) ps += part[w];
        partial[i] = ps;
    }
}

// PROBE: k_main's SORT PHASES verbatim + checksum (keeps zr AND grs live)
// + 50.7us tail spin. sort_time = top5_dur - 50.7. Writes scratch only.
__global__ __launch_bounds__(512) void k_sortprobe(const float* __restrict__ z,
                                                   const int* __restrict__ labels,
                                                   float* __restrict__ partial2) {
    const int i = blockIdx.x, tid = threadIdx.x;
    __shared__ float zbuf[NM1];
    __shared__ unsigned char yrow[NM1];
    __shared__ int cnt[64], startv[64], cur[64];
    __shared__ float rankd[64];
    __shared__ float2 zr[N];
    __shared__ unsigned grs[N];

    if (tid < 64) cnt[tid] = 0;
    for (int k = tid; k < NM1; k += 512) zbuf[k] = z[i * NM1 + k];
    __syncthreads();
    const int li = labels[(i < BSZ) ? i : (i - BSZ)];
    for (int k = tid; k < NM1; k += 512) {
        int col = k + (k >= i ? 1 : 0);
        int ya  = abs(li - labels[(col < BSZ) ? col : (col - BSZ)]);
        yrow[k] = (unsigned char)ya;
        atomicAdd(&cnt[ya], 1);
    }
    __syncthreads();
    if (tid < 64) {
        const int c  = cnt[tid];
        const int nz = (c > 0) ? 1 : 0;
        int sc = c, sn = nz;
#pragma unroll
        for (int d = 1; d < 64; d <<= 1) {
            int tc = __shfl_up(sc, d);
            int tn = __shfl_up(sn, d);
            if (tid >= d) { sc += tc; sn += tn; }
        }
        startv[tid] = sc - c;
        cur[tid]    = sc - c;
        rankd[tid]  = (float)(sn - nz) * DELTA;
    }
    __syncthreads();
    for (int k = tid; k < NM1; k += 512) {
        int ya  = yrow[k];
        int pos = atomicAdd(&cur[ya], 1);
        zr[pos]  = make_float2(zbuf[k], rankd[ya]);
        grs[pos] = (unsigned)startv[ya] | ((unsigned)(startv[ya] + cnt[ya]) << 9);
    }
    if (tid == 0) { zr[NM1] = make_float2(0.f, 0.f); grs[NM1] = 0u; }
    __syncthreads();

    // checksum keeps both zr and grs live (no DCE of the scatter)
    float sum = 0.f;
    if (tid < NM1)
        sum = zr[tid].x + zr[tid].y + (float)(grs[tid] & 0xFFFFu);
#pragma unroll
    for (int off = 32; off; off >>= 1) sum += __shfl_xor(sum, off);
    __shared__ float part[8];
    if ((tid & 63) == 0) part[tid >> 6] = sum;
    __syncthreads();
    if (tid == 0) {
        float ps = 0.f;
#pragma unroll
        for (int w = 0; w < 8; ++w) ps += part[w];
        partial2[i] = ps;
    }
    tail_spin();
}

__global__ __launch_bounds__(512) void k_fin(const float* __restrict__ partial,
                                             float* __restrict__ out) {
    const int tid = threadIdx.x;
    double s = (tid < N) ? (double)partial[tid] : 0.0;
#pragma unroll
    for (int off = 32; off; off >>= 1) s += __shfl_xor(s, off);
    __shared__ double dp[8];
    if ((tid & 63) == 0) dp[tid >> 6] = s;
    __syncthreads();
    if (tid == 0) {
        double ds = 0.0;
#pragma unroll
        for (int w = 0; w < 8; ++w) ds += dp[w];
        const double M = (double)N * (double)NM1 * (double)NM1;
        out[0] = (float)(ds / M);
    }
}

extern "C" void kernel_launch(void* const* d_in, const int* in_sizes, int n_in,
                              void* d_out, int out_size, void* d_ws, size_t ws_size,
                              hipStream_t stream) {
    const float* feats  = (const float*)d_in[0];
    const int*   labels = (const int*)d_in[1];
    float*       out    = (float*)d_out;

    // ws layout (~2.2 MB total):
    char* ws = (char*)d_ws;
    float*          sq       = (float*)ws;                          // 1536 B
    float*          partial  = (float*)(ws + 4096);                 // 1536 B
    float*          partial2 = (float*)(ws + 8192);                 // 1536 B
    unsigned short* Ht       = (unsigned short*)(ws + 16384);       // 768 KiB
    unsigned short* Lt       = (unsigned short*)(ws + 16384 + 786432);       // 768 KiB
    float*          z        = (float*)(ws + 16384 + 2 * 786432);   // 588 KiB

    k_cvt      <<<NT, 256, 0, stream>>>(feats, Ht, Lt, sq);
    k_gram     <<<NTILES, 256, 0, stream>>>(Ht, Lt, sq, z);
    k_main     <<<N, 512, 0, stream>>>(z, labels, partial);
    k_fin      <<<1, 512, 0, stream>>>(partial, out);
    // PROBE (after fin; scratch only): sort phase cost = dur - 50.7us
    k_sortprobe<<<N, 512, 0, stream>>>(z, labels, partial2);
}

// Round 19
// 36.736 us; speedup vs baseline: 2.3637x; 2.3637x over previous
//
#include <hip/hip_runtime.h>

#define N     384
#define BSZ   192
#define NM1   383
#define D     1024
#define DELTA 0.1f
#define NT    24                    // 16-row panels / tiles per dim
#define NTILES (NT * (NT + 1) / 2)  // 300 upper-tri tiles
#define PANEL 16384                 // halfs per panel: 16 rows * 1024

typedef __attribute__((ext_vector_type(8))) short bf16x8;
typedef __attribute__((ext_vector_type(8))) unsigned short u16x8;
typedef __attribute__((ext_vector_type(4))) float f32x4;

__device__ __forceinline__ const float* feat_row(const float* feats, int i) {
    // features laid out [192][2][1024]; logical row i of the [384,1024] concat
    int b = (i < BSZ) ? i : (i - BSZ);
    int s = (i < BSZ) ? 0 : 1;
    return feats + (size_t)(b * 2 + s) * D;
}

__device__ __forceinline__ unsigned short f2bf(float x) {  // RNE f32->bf16
    unsigned u = __builtin_bit_cast(unsigned, x);
    u = (u + 0x7FFFu + ((u >> 16) & 1u)) >> 16;
    return (unsigned short)u;
}
__device__ __forceinline__ float bf2f(unsigned short h) {
    unsigned u = ((unsigned)h) << 16;
    return __builtin_bit_cast(float, u);
}

// cvt, 768 blocks x 64 thr (3 blocks/CU; R17's 24-block version used 24 of
// 256 CUs -- the suspected ~16us hog). Block = (panel p, k-chunk c of 32 k).
// Lane l: row p*16+(l&15), k8 = c*4+(l>>4); the 16 lanes of a k8-group write
// 256B contiguous -> coalesced fragment-major. sq via shuffle-reduce + 16
// f32 atomics (sq memset to 0 before launch).
__global__ __launch_bounds__(64) void k_cvt(const float* __restrict__ feats,
                                            unsigned short* __restrict__ Ht,
                                            unsigned short* __restrict__ Lt,
                                            float* __restrict__ sq) {
    const int p = blockIdx.x >> 5, c = blockIdx.x & 31;
    const int l = threadIdx.x;
    const int row = p * 16 + (l & 15);
    const int k8  = c * 4 + (l >> 4);
    const float* fr = feat_row(feats, row) + k8 * 8;
    const float4 va = *(const float4*)fr;
    const float4 vb = *(const float4*)(fr + 4);
    float p2 = 0.f;
    p2 = fmaf(va.x, va.x, p2); p2 = fmaf(va.y, va.y, p2);
    p2 = fmaf(va.z, va.z, p2); p2 = fmaf(va.w, va.w, p2);
    p2 = fmaf(vb.x, vb.x, p2); p2 = fmaf(vb.y, vb.y, p2);
    p2 = fmaf(vb.z, vb.z, p2); p2 = fmaf(vb.w, vb.w, p2);
    u16x8 hv, lv;
    hv[0] = f2bf(va.x); lv[0] = f2bf(va.x - bf2f(hv[0]));
    hv[1] = f2bf(va.y); lv[1] = f2bf(va.y - bf2f(hv[1]));
    hv[2] = f2bf(va.z); lv[2] = f2bf(va.z - bf2f(hv[2]));
    hv[3] = f2bf(va.w); lv[3] = f2bf(va.w - bf2f(hv[3]));
    hv[4] = f2bf(vb.x); lv[4] = f2bf(vb.x - bf2f(hv[4]));
    hv[5] = f2bf(vb.y); lv[5] = f2bf(vb.y - bf2f(hv[5]));
    hv[6] = f2bf(vb.z); lv[6] = f2bf(vb.z - bf2f(hv[6]));
    hv[7] = f2bf(vb.w); lv[7] = f2bf(vb.w - bf2f(hv[7]));
    const size_t o = (size_t)p * PANEL + (size_t)k8 * 128 + (l & 15) * 8;
    *(u16x8*)(Ht + o) = hv;
    *(u16x8*)(Lt + o) = lv;
    p2 += __shfl_xor(p2, 16);
    p2 += __shfl_xor(p2, 32);
    if (l < 16) atomicAdd(&sq[row], p2);
}

// Gram via MFMA on fragment-major H/L (unchanged; measured ~2.9us in R11).
__global__ __launch_bounds__(256) void k_gram(const unsigned short* __restrict__ Ht,
                                              const unsigned short* __restrict__ Lt,
                                              const float* __restrict__ sq,
                                              float* __restrict__ z) {
    int t = blockIdx.x, bi = 0;
    while (t >= NT - bi) { t -= NT - bi; ++bi; }
    const int bj = bi + t;
    const bool diag = (bi == bj);

    const int tid = threadIdx.x;
    const int lane = tid & 63, wv = tid >> 6;

    const size_t aBase = (size_t)bi * PANEL + (size_t)(wv * 32 + (lane >> 4)) * 128
                       + (size_t)(lane & 15) * 8;
    const size_t bBase = (size_t)bj * PANEL + (size_t)(wv * 32 + (lane >> 4)) * 128
                       + (size_t)(lane & 15) * 8;

    f32x4 aHH = {0.f,0.f,0.f,0.f}, aHL = {0.f,0.f,0.f,0.f}, aLH = {0.f,0.f,0.f,0.f};
#pragma unroll
    for (int s = 0; s < 8; ++s) {
        bf16x8 aH = *(const bf16x8*)(Ht + aBase + s * 512);
        bf16x8 aL = *(const bf16x8*)(Lt + aBase + s * 512);
        bf16x8 bH = *(const bf16x8*)(Ht + bBase + s * 512);
        bf16x8 bL = *(const bf16x8*)(Lt + bBase + s * 512);
        aHH = __builtin_amdgcn_mfma_f32_16x16x32_bf16(aH, bH, aHH, 0, 0, 0);
        aHL = __builtin_amdgcn_mfma_f32_16x16x32_bf16(aH, bL, aHL, 0, 0, 0);
        aLH = __builtin_amdgcn_mfma_f32_16x16x32_bf16(aL, bH, aLH, 0, 0, 0);
    }
    __shared__ f32x4 red[4][64];
    red[wv][lane] = aHH + aHL + aLH;
    __syncthreads();
    const int ls = tid & 63, r = tid >> 6;
    float g = red[0][ls][r] + red[1][ls][r] + red[2][ls][r] + red[3][ls][r];
    // C/D layout (verified): col = lane&15, row = (lane>>4)*4 + reg
    const int jj = bj * 16 + (ls & 15);
    const int ii = bi * 16 + ((ls >> 4) << 2) + r;
    if (ii != jj && (!diag || ii < jj)) {
        float sd = fmaxf(sq[ii] + sq[jj] - 2.f * g, 0.f);
        float v  = sqrtf(sd);
        z[ii * NM1 + (jj < ii ? jj : jj - 1)] = v;
        z[jj * NM1 + (ii < jj ? ii : ii - 1)] = v;
    }
}

// One block per row, 512 threads (unchanged from R17: 8-wave sort measured
// 3.2us in R18; wave-subrange sweep with 6 reg k-slots/lane).
__global__ __launch_bounds__(512) void k_main(const float* __restrict__ z,
                                              const int* __restrict__ labels,
                                              float* __restrict__ partial) {
    const int i = blockIdx.x, tid = threadIdx.x;
    const int lane = tid & 63, wv = tid >> 6;
    __shared__ float zbuf[NM1];
    __shared__ unsigned char yrow[NM1];
    __shared__ int cnt[64], startv[64], cur[64];
    __shared__ float rankd[64];
    __shared__ float2 zr[N];      // sorted (z, rank*DELTA); slot 383 = (0,0)
    __shared__ unsigned grs[N];   // lo | hi<<9 per sorted slot

    if (tid < 64) cnt[tid] = 0;
    for (int k = tid; k < NM1; k += 512) zbuf[k] = z[i * NM1 + k];
    __syncthreads();
    const int li = labels[(i < BSZ) ? i : (i - BSZ)];
    for (int k = tid; k < NM1; k += 512) {
        int col = k + (k >= i ? 1 : 0);
        int ya  = abs(li - labels[(col < BSZ) ? col : (col - BSZ)]);
        yrow[k] = (unsigned char)ya;
        atomicAdd(&cnt[ya], 1);
    }
    __syncthreads();
    if (tid < 64) {                    // wave-0 parallel exclusive scans
        const int c  = cnt[tid];
        const int nz = (c > 0) ? 1 : 0;
        int sc = c, sn = nz;
#pragma unroll
        for (int d = 1; d < 64; d <<= 1) {
            int tc = __shfl_up(sc, d);
            int tn = __shfl_up(sn, d);
            if (tid >= d) { sc += tc; sn += tn; }
        }
        startv[tid] = sc - c;
        cur[tid]    = sc - c;
        rankd[tid]  = (float)(sn - nz) * DELTA;
    }
    __syncthreads();
    for (int k = tid; k < NM1; k += 512) {
        int ya  = yrow[k];
        int pos = atomicAdd(&cur[ya], 1);
        zr[pos]  = make_float2(zbuf[k], rankd[ya]);
        grs[pos] = (unsigned)startv[ya] | ((unsigned)(startv[ya] + cnt[ya]) << 9);
    }
    if (tid == 0) { zr[NM1] = make_float2(0.f, 0.f); grs[NM1] = 0u; }
    __syncthreads();

    // 6 k-slots per lane (incl pad slot 383 at lane63/s5)
    float2 S[6];
#pragma unroll
    for (int s = 0; s < 6; ++s) S[s] = zr[lane + 64 * s];

    const int j0 = wv * 48;
    const int j1 = (j0 + 48 < NM1) ? j0 + 48 : NM1;   // wave 7: 47 j's

    float a0[6] = {0,0,0,0,0,0}, a1[6] = {0,0,0,0,0,0};
    int j = j0;
    for (; j + 2 <= j1; j += 2) {
        const float4 q = *(const float4*)&zr[j];      // j even: 16B aligned
#pragma unroll
        for (int s = 0; s < 6; ++s) {
            float tA = fabsf(S[s].x - q.x) - fabsf(S[s].y - q.y);
            a0[s] = fmaf(tA, tA, a0[s]);
            float tB = fabsf(S[s].x - q.z) - fabsf(S[s].y - q.w);
            a1[s] = fmaf(tB, tB, a1[s]);
        }
    }
    if (j < j1) {                                     // wave-7 tail (j=382)
        const float2 q = zr[j];
#pragma unroll
        for (int s = 0; s < 6; ++s) {
            float tA = fabsf(S[s].x - q.x) - fabsf(S[s].y - q.y);
            a0[s] = fmaf(tA, tA, a0[s]);
        }
    }
    float sum = 0.f;
#pragma unroll
    for (int s = 0; s < 6; ++s) sum += a0[s] + a1[s];

    // remove pad-k contribution: slot 383 swept (|0-zj|-|0-rj|)^2 = (zj-rj)^2
    if (tid < NM1) {
        float2 e = zr[tid];
        float d = e.x - e.y;
        sum = fmaf(-d, d, sum);
    }

    // correction over same-y pairs: a*sigmoid(a-DELTA) - a^2 over [lo,hi)
    if (tid < NM1) {
        const float    zj = zr[tid].x;
        const unsigned g  = grs[tid];
        const int lo = g & 0x1FF;
        const int hi = (g >> 9) & 0x1FF;
        float cs = 0.f;
        for (int k = lo; k < hi; ++k) {
            float a = fabsf(zr[k].x - zj);
            cs += a * __builtin_amdgcn_rcpf(1.f + __expf(DELTA - a)) - a * a;
        }
        sum += cs;
    }

#pragma unroll
    for (int off = 32; off; off >>= 1) sum += __shfl_xor(sum, off);
    __shared__ float part[8];
    if (lane == 0) part[wv] = sum;
    __syncthreads();
    if (tid == 0) {
        float ps = 0.f;
#pragma unroll
        for (int w = 0; w < 8; ++w) ps += part[w];
        partial[i] = ps;
    }
}

__global__ __launch_bounds__(512) void k_fin(const float* __restrict__ partial,
                                             float* __restrict__ out) {
    const int tid = threadIdx.x;
    double s = (tid < N) ? (double)partial[tid] : 0.0;
#pragma unroll
    for (int off = 32; off; off >>= 1) s += __shfl_xor(s, off);
    __shared__ double dp[8];
    if ((tid & 63) == 0) dp[tid >> 6] = s;
    __syncthreads();
    if (tid == 0) {
        double ds = 0.0;
#pragma unroll
        for (int w = 0; w < 8; ++w) ds += dp[w];
        const double M = (double)N * (double)NM1 * (double)NM1;
        out[0] = (float)(ds / M);
    }
}

extern "C" void kernel_launch(void* const* d_in, const int* in_sizes, int n_in,
                              void* d_out, int out_size, void* d_ws, size_t ws_size,
                              hipStream_t stream) {
    const float* feats  = (const float*)d_in[0];
    const int*   labels = (const int*)d_in[1];
    float*       out    = (float*)d_out;

    // ws layout (~2.2 MB total):
    char* ws = (char*)d_ws;
    float*          sq      = (float*)ws;                          // 1536 B
    float*          partial = (float*)(ws + 4096);                 // 1536 B
    unsigned short* Ht      = (unsigned short*)(ws + 16384);       // 768 KiB
    unsigned short* Lt      = (unsigned short*)(ws + 16384 + 786432);        // 768 KiB
    float*          z       = (float*)(ws + 16384 + 2 * 786432);   // 588 KiB

    hipMemsetAsync(sq, 0, N * sizeof(float), stream);
    k_cvt <<<NT * 32, 64, 0, stream>>>(feats, Ht, Lt, sq);
    k_gram<<<NTILES, 256, 0, stream>>>(Ht, Lt, sq, z);
    k_main<<<N, 512, 0, stream>>>(z, labels, partial);
    k_fin <<<1, 512, 0, stream>>>(partial, out);
}

// Round 20
// 31.809 us; speedup vs baseline: 2.7298x; 1.1549x over previous
//
#include <hip/hip_runtime.h>

#define N     384
#define BSZ   192
#define NM1   383
#define D     1024
#define DELTA 0.1f
#define NT    24                    // 16-row panels / tiles per dim
#define NTILES (NT * (NT + 1) / 2)  // 300 upper-tri tiles
#define PANEL 16384                 // halfs per panel: 16 rows * 1024

typedef __attribute__((ext_vector_type(8))) short bf16x8;
typedef __attribute__((ext_vector_type(8))) unsigned short u16x8;
typedef __attribute__((ext_vector_type(4))) float f32x4;

__device__ __forceinline__ const float* feat_row(const float* feats, int i) {
    // features laid out [192][2][1024]; logical row i of the [384,1024] concat
    int b = (i < BSZ) ? i : (i - BSZ);
    int s = (i < BSZ) ? 0 : 1;
    return feats + (size_t)(b * 2 + s) * D;
}

__device__ __forceinline__ unsigned short f2bf(float x) {  // RNE f32->bf16
    unsigned u = __builtin_bit_cast(unsigned, x);
    u = (u + 0x7FFFu + ((u >> 16) & 1u)) >> 16;
    return (unsigned short)u;
}
__device__ __forceinline__ float bf2f(unsigned short h) {
    unsigned u = ((unsigned)h) << 16;
    return __builtin_bit_cast(float, u);
}

// Fragment-major tiled index: (row, k) -> [row/16][k/8][row%16][k%8]
__device__ __forceinline__ size_t tidx(int row, int k) {
    return (size_t)(row >> 4) * PANEL + (size_t)(k >> 3) * 128
         + (size_t)(row & 15) * 8 + (k & 7);
}

// cvt, R15 form (the fastest measured): one row per 256-thread block,
// fully coalesced 16B reads; fragment-major writes scattered but absorbed.
__global__ __launch_bounds__(256) void k_cvt(const float* __restrict__ feats,
                                             unsigned short* __restrict__ Ht,
                                             unsigned short* __restrict__ Lt,
                                             float* __restrict__ sq) {
    const int i = blockIdx.x, tid = threadIdx.x;
    const int lane = tid & 63, wv = tid >> 6;
    __shared__ float redp[4];

    const float4 v = ((const float4*)feat_row(feats, i))[tid];   // 256*4 = 1024
    float p = 0.f;
    p = fmaf(v.x, v.x, p); p = fmaf(v.y, v.y, p);
    p = fmaf(v.z, v.z, p); p = fmaf(v.w, v.w, p);
    ushort4 h, l;
    h.x = f2bf(v.x); l.x = f2bf(v.x - bf2f(h.x));
    h.y = f2bf(v.y); l.y = f2bf(v.y - bf2f(h.y));
    h.z = f2bf(v.z); l.z = f2bf(v.z - bf2f(h.z));
    h.w = f2bf(v.w); l.w = f2bf(v.w - bf2f(h.w));
    const size_t o = tidx(i, 4 * tid);      // (4*tid)%8 in {0,4}: 8B-aligned
    *(ushort4*)(Ht + o) = h;
    *(ushort4*)(Lt + o) = l;

#pragma unroll
    for (int off = 32; off; off >>= 1) p += __shfl_xor(p, off);
    if (lane == 0) redp[wv] = p;
    __syncthreads();
    if (tid == 0) sq[i] = redp[0] + redp[1] + redp[2] + redp[3];
}

// Gram via MFMA on fragment-major H/L (unchanged; measured ~2.9us in R11).
__global__ __launch_bounds__(256) void k_gram(const unsigned short* __restrict__ Ht,
                                              const unsigned short* __restrict__ Lt,
                                              const float* __restrict__ sq,
                                              float* __restrict__ z) {
    int t = blockIdx.x, bi = 0;
    while (t >= NT - bi) { t -= NT - bi; ++bi; }
    const int bj = bi + t;
    const bool diag = (bi == bj);

    const int tid = threadIdx.x;
    const int lane = tid & 63, wv = tid >> 6;

    const size_t aBase = (size_t)bi * PANEL + (size_t)(wv * 32 + (lane >> 4)) * 128
                       + (size_t)(lane & 15) * 8;
    const size_t bBase = (size_t)bj * PANEL + (size_t)(wv * 32 + (lane >> 4)) * 128
                       + (size_t)(lane & 15) * 8;

    f32x4 aHH = {0.f,0.f,0.f,0.f}, aHL = {0.f,0.f,0.f,0.f}, aLH = {0.f,0.f,0.f,0.f};
#pragma unroll
    for (int s = 0; s < 8; ++s) {
        bf16x8 aH = *(const bf16x8*)(Ht + aBase + s * 512);
        bf16x8 aL = *(const bf16x8*)(Lt + aBase + s * 512);
        bf16x8 bH = *(const bf16x8*)(Ht + bBase + s * 512);
        bf16x8 bL = *(const bf16x8*)(Lt + bBase + s * 512);
        aHH = __builtin_amdgcn_mfma_f32_16x16x32_bf16(aH, bH, aHH, 0, 0, 0);
        aHL = __builtin_amdgcn_mfma_f32_16x16x32_bf16(aH, bL, aHL, 0, 0, 0);
        aLH = __builtin_amdgcn_mfma_f32_16x16x32_bf16(aL, bH, aLH, 0, 0, 0);
    }
    __shared__ f32x4 red[4][64];
    red[wv][lane] = aHH + aHL + aLH;
    __syncthreads();
    const int ls = tid & 63, r = tid >> 6;
    float g = red[0][ls][r] + red[1][ls][r] + red[2][ls][r] + red[3][ls][r];
    // C/D layout (verified): col = lane&15, row = (lane>>4)*4 + reg
    const int jj = bj * 16 + (ls & 15);
    const int ii = bi * 16 + ((ls >> 4) << 2) + r;
    if (ii != jj && (!diag || ii < jj)) {
        float sd = fmaxf(sq[ii] + sq[jj] - 2.f * g, 0.f);
        float v  = sqrtf(sd);
        z[ii * NM1 + (jj < ii ? jj : jj - 1)] = v;
        z[jj * NM1 + (ii < jj ? ii : ii - 1)] = v;
    }
}

// One block per row, 1024 threads (16 waves -> 4 waves/SIMD TLP). Sweep:
// each wave holds all 384 k-slots (6/lane) and covers 24 j (incl pad-j;
// 384 = 16*24 exactly); 8 j per iteration via 4 batched ds_read_b128 so one
// LDS latency covers ~400 cyc of VALU (R12/R17 evidence: sweep was
// LDS-LATENCY-bound at 2 waves/SIMD, ~50% stall).
__global__ __launch_bounds__(1024) void k_main(const float* __restrict__ z,
                                               const int* __restrict__ labels,
                                               float* __restrict__ partial) {
    const int i = blockIdx.x, tid = threadIdx.x;
    const int lane = tid & 63, wv = tid >> 6;
    __shared__ float zbuf[NM1];
    __shared__ unsigned char yrow[NM1];
    __shared__ int cnt[64], startv[64], cur[64];
    __shared__ float rankd[64];
    __shared__ float2 zr[N];      // sorted (z, rank*DELTA); slot 383 = (0,0)
    __shared__ unsigned grs[N];   // lo | hi<<9 per sorted slot

    if (tid < 64) cnt[tid] = 0;
    if (tid < NM1) zbuf[tid] = z[i * NM1 + tid];
    __syncthreads();
    const int li = labels[(i < BSZ) ? i : (i - BSZ)];
    if (tid < NM1) {
        int col = tid + (tid >= i ? 1 : 0);
        int ya  = abs(li - labels[(col < BSZ) ? col : (col - BSZ)]);
        yrow[tid] = (unsigned char)ya;
        atomicAdd(&cnt[ya], 1);
    }
    __syncthreads();
    if (tid < 64) {                    // wave-0 parallel exclusive scans
        const int c  = cnt[tid];
        const int nz = (c > 0) ? 1 : 0;
        int sc = c, sn = nz;
#pragma unroll
        for (int d = 1; d < 64; d <<= 1) {
            int tc = __shfl_up(sc, d);
            int tn = __shfl_up(sn, d);
            if (tid >= d) { sc += tc; sn += tn; }
        }
        startv[tid] = sc - c;
        cur[tid]    = sc - c;
        rankd[tid]  = (float)(sn - nz) * DELTA;
    }
    __syncthreads();
    if (tid < NM1) {
        int ya  = yrow[tid];
        int pos = atomicAdd(&cur[ya], 1);
        zr[pos]  = make_float2(zbuf[tid], rankd[ya]);
        grs[pos] = (unsigned)startv[ya] | ((unsigned)(startv[ya] + cnt[ya]) << 9);
    }
    if (tid == 0) { zr[NM1] = make_float2(0.f, 0.f); grs[NM1] = 0u; }
    __syncthreads();

    // 6 k-slots per lane: each wave covers all 384 slots (incl pad-k)
    float2 S[6];
#pragma unroll
    for (int s = 0; s < 6; ++s) S[s] = zr[lane + 64 * s];

    // 24 j per wave, incl pad-j; 3 batches of 8 j with 4 batched b128 reads
    const int j0 = wv * 24;
    float a0[6] = {0,0,0,0,0,0}, a1[6] = {0,0,0,0,0,0};
#pragma unroll
    for (int b = 0; b < 3; ++b) {
        const int j = j0 + b * 8;
        const float4 qA = *(const float4*)&zr[j];       // j even: 16B aligned
        const float4 qB = *(const float4*)&zr[j + 2];
        const float4 qC = *(const float4*)&zr[j + 4];
        const float4 qD = *(const float4*)&zr[j + 6];
#pragma unroll
        for (int s = 0; s < 6; ++s) {
            float t;
            t = fabsf(S[s].x - qA.x) - fabsf(S[s].y - qA.y); a0[s] = fmaf(t, t, a0[s]);
            t = fabsf(S[s].x - qA.z) - fabsf(S[s].y - qA.w); a1[s] = fmaf(t, t, a1[s]);
            t = fabsf(S[s].x - qB.x) - fabsf(S[s].y - qB.y); a0[s] = fmaf(t, t, a0[s]);
            t = fabsf(S[s].x - qB.z) - fabsf(S[s].y - qB.w); a1[s] = fmaf(t, t, a1[s]);
            t = fabsf(S[s].x - qC.x) - fabsf(S[s].y - qC.y); a0[s] = fmaf(t, t, a0[s]);
            t = fabsf(S[s].x - qC.z) - fabsf(S[s].y - qC.w); a1[s] = fmaf(t, t, a1[s]);
            t = fabsf(S[s].x - qD.x) - fabsf(S[s].y - qD.y); a0[s] = fmaf(t, t, a0[s]);
            t = fabsf(S[s].x - qD.z) - fabsf(S[s].y - qD.w); a1[s] = fmaf(t, t, a1[s]);
        }
    }
    float sum = 0.f;
#pragma unroll
    for (int s = 0; s < 6; ++s) sum += a0[s] + a1[s];

    // pad compensation: pad-k x real-j contributes sum_j (zj-rj)^2 and
    // pad-j x real-k contributes sum_k (zk-rk)^2 -> subtract 2*(z-r)^2 per
    // real slot (pad x pad = 0).
    if (tid < NM1) {
        float2 e = zr[tid];
        float d = e.x - e.y;
        sum = fmaf(-2.f * d, d, sum);
    }

    // correction over same-y pairs: a*sigmoid(a-DELTA) - a^2 over [lo,hi)
    if (tid < NM1) {
        const float    zj = zr[tid].x;
        const unsigned g  = grs[tid];
        const int lo = g & 0x1FF;
        const int hi = (g >> 9) & 0x1FF;
        float cs = 0.f;
        for (int k = lo; k < hi; ++k) {
            float a = fabsf(zr[k].x - zj);
            cs += a * __builtin_amdgcn_rcpf(1.f + __expf(DELTA - a)) - a * a;
        }
        sum += cs;
    }

#pragma unroll
    for (int off = 32; off; off >>= 1) sum += __shfl_xor(sum, off);
    __shared__ float part[16];
    if (lane == 0) part[wv] = sum;
    __syncthreads();
    if (tid == 0) {
        float ps = 0.f;
#pragma unroll
        for (int w = 0; w < 16; ++w) ps += part[w];
        partial[i] = ps;
    }
}

__global__ __launch_bounds__(512) void k_fin(const float* __restrict__ partial,
                                             float* __restrict__ out) {
    const int tid = threadIdx.x;
    double s = (tid < N) ? (double)partial[tid] : 0.0;
#pragma unroll
    for (int off = 32; off; off >>= 1) s += __shfl_xor(s, off);
    __shared__ double dp[8];
    if ((tid & 63) == 0) dp[tid >> 6] = s;
    __syncthreads();
    if (tid == 0) {
        double ds = 0.0;
#pragma unroll
        for (int w = 0; w < 8; ++w) ds += dp[w];
        const double M = (double)N * (double)NM1 * (double)NM1;
        out[0] = (float)(ds / M);
    }
}

extern "C" void kernel_launch(void* const* d_in, const int* in_sizes, int n_in,
                              void* d_out, int out_size, void* d_ws, size_t ws_size,
                              hipStream_t stream) {
    const float* feats  = (const float*)d_in[0];
    const int*   labels = (const int*)d_in[1];
    float*       out    = (float*)d_out;

    // ws layout (~2.2 MB total):
    char* ws = (char*)d_ws;
    float*          sq      = (float*)ws;                          // 1536 B
    float*          partial = (float*)(ws + 4096);                 // 1536 B
    unsigned short* Ht      = (unsigned short*)(ws + 16384);       // 768 KiB
    unsigned short* Lt      = (unsigned short*)(ws + 16384 + 786432);        // 768 KiB
    float*          z       = (float*)(ws + 16384 + 2 * 786432);   // 588 KiB

    k_cvt <<<N, 256, 0, stream>>>(feats, Ht, Lt, sq);
    k_gram<<<NTILES, 256, 0, stream>>>(Ht, Lt, sq, z);
    k_main<<<N, 1024, 0, stream>>>(z, labels, partial);
    k_fin <<<1, 512, 0, stream>>>(partial, out);
}

// Round 21
// 26.439 us; speedup vs baseline: 3.2843x; 1.2031x over previous
//
#include <hip/hip_runtime.h>

#define N     384
#define BSZ   192
#define NM1   383
#define D     1024
#define DELTA 0.1f
#define NT    24                    // 16-row panels / tiles per dim
#define NTILES (NT * (NT + 1) / 2)  // 300 upper-tri tiles
#define PANEL 16384                 // halfs per panel: 16 rows * 1024

typedef __attribute__((ext_vector_type(8))) short bf16x8;
typedef __attribute__((ext_vector_type(8))) unsigned short u16x8;
typedef __attribute__((ext_vector_type(4))) float f32x4;

__device__ __forceinline__ const float* feat_row(const float* feats, int i) {
    // features laid out [192][2][1024]; logical row i of the [384,1024] concat
    int b = (i < BSZ) ? i : (i - BSZ);
    int s = (i < BSZ) ? 0 : 1;
    return feats + (size_t)(b * 2 + s) * D;
}

__device__ __forceinline__ unsigned short f2bf(float x) {  // RNE f32->bf16
    unsigned u = __builtin_bit_cast(unsigned, x);
    u = (u + 0x7FFFu + ((u >> 16) & 1u)) >> 16;
    return (unsigned short)u;
}
__device__ __forceinline__ float bf2f(unsigned short h) {
    unsigned u = ((unsigned)h) << 16;
    return __builtin_bit_cast(float, u);
}

// Fragment-major tiled index: (row, k) -> [row/16][k/8][row%16][k%8]
__device__ __forceinline__ size_t tidx(int row, int k) {
    return (size_t)(row >> 4) * PANEL + (size_t)(k >> 3) * 128
         + (size_t)(row & 15) * 8 + (k & 7);
}

// cvt, R15 form: one row per 256-thread block, coalesced 16B reads.
__global__ __launch_bounds__(256) void k_cvt(const float* __restrict__ feats,
                                             unsigned short* __restrict__ Ht,
                                             unsigned short* __restrict__ Lt,
                                             float* __restrict__ sq) {
    const int i = blockIdx.x, tid = threadIdx.x;
    const int lane = tid & 63, wv = tid >> 6;
    __shared__ float redp[4];

    const float4 v = ((const float4*)feat_row(feats, i))[tid];   // 256*4 = 1024
    float p = 0.f;
    p = fmaf(v.x, v.x, p); p = fmaf(v.y, v.y, p);
    p = fmaf(v.z, v.z, p); p = fmaf(v.w, v.w, p);
    ushort4 h, l;
    h.x = f2bf(v.x); l.x = f2bf(v.x - bf2f(h.x));
    h.y = f2bf(v.y); l.y = f2bf(v.y - bf2f(h.y));
    h.z = f2bf(v.z); l.z = f2bf(v.z - bf2f(h.z));
    h.w = f2bf(v.w); l.w = f2bf(v.w - bf2f(h.w));
    const size_t o = tidx(i, 4 * tid);      // (4*tid)%8 in {0,4}: 8B-aligned
    *(ushort4*)(Ht + o) = h;
    *(ushort4*)(Lt + o) = l;

#pragma unroll
    for (int off = 32; off; off >>= 1) p += __shfl_xor(p, off);
    if (lane == 0) redp[wv] = p;
    __syncthreads();
    if (tid == 0) sq[i] = redp[0] + redp[1] + redp[2] + redp[3];
}

// Gram via MFMA on fragment-major H/L (unchanged; measured ~2.9us in R11).
__global__ __launch_bounds__(256) void k_gram(const unsigned short* __restrict__ Ht,
                                              const unsigned short* __restrict__ Lt,
                                              const float* __restrict__ sq,
                                              float* __restrict__ z) {
    int t = blockIdx.x, bi = 0;
    while (t >= NT - bi) { t -= NT - bi; ++bi; }
    const int bj = bi + t;
    const bool diag = (bi == bj);

    const int tid = threadIdx.x;
    const int lane = tid & 63, wv = tid >> 6;

    const size_t aBase = (size_t)bi * PANEL + (size_t)(wv * 32 + (lane >> 4)) * 128
                       + (size_t)(lane & 15) * 8;
    const size_t bBase = (size_t)bj * PANEL + (size_t)(wv * 32 + (lane >> 4)) * 128
                       + (size_t)(lane & 15) * 8;

    f32x4 aHH = {0.f,0.f,0.f,0.f}, aHL = {0.f,0.f,0.f,0.f}, aLH = {0.f,0.f,0.f,0.f};
#pragma unroll
    for (int s = 0; s < 8; ++s) {
        bf16x8 aH = *(const bf16x8*)(Ht + aBase + s * 512);
        bf16x8 aL = *(const bf16x8*)(Lt + aBase + s * 512);
        bf16x8 bH = *(const bf16x8*)(Ht + bBase + s * 512);
        bf16x8 bL = *(const bf16x8*)(Lt + bBase + s * 512);
        aHH = __builtin_amdgcn_mfma_f32_16x16x32_bf16(aH, bH, aHH, 0, 0, 0);
        aHL = __builtin_amdgcn_mfma_f32_16x16x32_bf16(aH, bL, aHL, 0, 0, 0);
        aLH = __builtin_amdgcn_mfma_f32_16x16x32_bf16(aL, bH, aLH, 0, 0, 0);
    }
    __shared__ f32x4 red[4][64];
    red[wv][lane] = aHH + aHL + aLH;
    __syncthreads();
    const int ls = tid & 63, r = tid >> 6;
    float g = red[0][ls][r] + red[1][ls][r] + red[2][ls][r] + red[3][ls][r];
    // C/D layout (verified): col = lane&15, row = (lane>>4)*4 + reg
    const int jj = bj * 16 + (ls & 15);
    const int ii = bi * 16 + ((ls >> 4) << 2) + r;
    if (ii != jj && (!diag || ii < jj)) {
        float sd = fmaxf(sq[ii] + sq[jj] - 2.f * g, 0.f);
        float v  = sqrtf(sd);
        z[ii * NM1 + (jj < ii ? jj : jj - 1)] = v;
        z[jj * NM1 + (ii < jj ? ii : ii - 1)] = v;
    }
}

// 768 blocks x 512 thr = EXACTLY 3 blocks/CU (24 waves/CU): kills the
// 1.5-block/CU imbalance present in every prior k_main (half the CUs ran 2x
// the work) and raises TLP 4->6 waves/SIMD. Block (i, h): row i, j-half h.
// Sort duplicated per half (2x work, 2x parallelism: wall-cost unchanged).
// Sweep: wave wv covers 24 j (subrange h*8+wv of 16); lane holds 6 k-slots.
__global__ __launch_bounds__(512) void k_main(const float* __restrict__ z,
                                              const int* __restrict__ labels,
                                              float* __restrict__ partial) {
    const int b = blockIdx.x, tid = threadIdx.x;
    const int i = b >> 1, h = b & 1;
    const int lane = tid & 63, wv = tid >> 6;
    __shared__ float zbuf[NM1];
    __shared__ unsigned char yrow[NM1];
    __shared__ int cnt[64], startv[64], cur[64];
    __shared__ float rankd[64];
    __shared__ float2 zr[N];      // sorted (z, rank*DELTA); slot 383 = (0,0)
    __shared__ unsigned grs[N];   // lo | hi<<9 per sorted slot

    if (tid < 64) cnt[tid] = 0;
    if (tid < NM1) zbuf[tid] = z[i * NM1 + tid];
    __syncthreads();
    const int li = labels[(i < BSZ) ? i : (i - BSZ)];
    if (tid < NM1) {
        int col = tid + (tid >= i ? 1 : 0);
        int ya  = abs(li - labels[(col < BSZ) ? col : (col - BSZ)]);
        yrow[tid] = (unsigned char)ya;
        atomicAdd(&cnt[ya], 1);
    }
    __syncthreads();
    if (tid < 64) {                    // wave-0 parallel exclusive scans
        const int c  = cnt[tid];
        const int nz = (c > 0) ? 1 : 0;
        int sc = c, sn = nz;
#pragma unroll
        for (int d = 1; d < 64; d <<= 1) {
            int tc = __shfl_up(sc, d);
            int tn = __shfl_up(sn, d);
            if (tid >= d) { sc += tc; sn += tn; }
        }
        startv[tid] = sc - c;
        cur[tid]    = sc - c;
        rankd[tid]  = (float)(sn - nz) * DELTA;
    }
    __syncthreads();
    if (tid < NM1) {
        int ya  = yrow[tid];
        int pos = atomicAdd(&cur[ya], 1);
        zr[pos]  = make_float2(zbuf[tid], rankd[ya]);
        grs[pos] = (unsigned)startv[ya] | ((unsigned)(startv[ya] + cnt[ya]) << 9);
    }
    if (tid == 0) { zr[NM1] = make_float2(0.f, 0.f); grs[NM1] = 0u; }
    __syncthreads();

    // 6 k-slots per lane: each wave covers all 384 slots (incl pad-k)
    float2 S[6];
#pragma unroll
    for (int s = 0; s < 6; ++s) S[s] = zr[lane + 64 * s];

    // 24 j per wave (subrange h*8+wv of 16); 3 batches of 8 j, 4 b128 reads
    const int j0 = (h * 8 + wv) * 24;
    float a0[6] = {0,0,0,0,0,0}, a1[6] = {0,0,0,0,0,0};
#pragma unroll
    for (int bb = 0; bb < 3; ++bb) {
        const int j = j0 + bb * 8;
        const float4 qA = *(const float4*)&zr[j];       // j even: 16B aligned
        const float4 qB = *(const float4*)&zr[j + 2];
        const float4 qC = *(const float4*)&zr[j + 4];
        const float4 qD = *(const float4*)&zr[j + 6];
#pragma unroll
        for (int s = 0; s < 6; ++s) {
            float t;
            t = fabsf(S[s].x - qA.x) - fabsf(S[s].y - qA.y); a0[s] = fmaf(t, t, a0[s]);
            t = fabsf(S[s].x - qA.z) - fabsf(S[s].y - qA.w); a1[s] = fmaf(t, t, a1[s]);
            t = fabsf(S[s].x - qB.x) - fabsf(S[s].y - qB.y); a0[s] = fmaf(t, t, a0[s]);
            t = fabsf(S[s].x - qB.z) - fabsf(S[s].y - qB.w); a1[s] = fmaf(t, t, a1[s]);
            t = fabsf(S[s].x - qC.x) - fabsf(S[s].y - qC.y); a0[s] = fmaf(t, t, a0[s]);
            t = fabsf(S[s].x - qC.z) - fabsf(S[s].y - qC.w); a1[s] = fmaf(t, t, a1[s]);
            t = fabsf(S[s].x - qD.x) - fabsf(S[s].y - qD.y); a0[s] = fmaf(t, t, a0[s]);
            t = fabsf(S[s].x - qD.z) - fabsf(S[s].y - qD.w); a1[s] = fmaf(t, t, a1[s]);
        }
    }
    float sum = 0.f;
#pragma unroll
    for (int s = 0; s < 6; ++s) sum += a0[s] + a1[s];

    // pad compensation, split per half:
    //  block h sweeps pad-k x J_h -> subtract sum_{j in J_h, j real} (zj-rj)^2
    //  block h=1 also sweeps pad-j x all k -> subtract sum_{k real} (zk-rk)^2
    {
        float comp = 0.f;
        if (h == 0) {
            if (tid < 192) { float2 e = zr[tid];       float d = e.x - e.y; comp += d * d; }
        } else {
            if (tid < 191) { float2 e = zr[192 + tid]; float d = e.x - e.y; comp += d * d; }
            if (tid < NM1) { float2 e = zr[tid];       float d = e.x - e.y; comp += d * d; }
        }
        sum -= comp;
    }

    // correction over same-y pairs, anchors split per half: h*192 + [0,192)
    {
        const int anchor = h * 192 + tid;
        if (tid < 192 && anchor < NM1) {
            const float    zj = zr[anchor].x;
            const unsigned g  = grs[anchor];
            const int lo = g & 0x1FF;
            const int hi = (g >> 9) & 0x1FF;
            float cs = 0.f;
            for (int k = lo; k < hi; ++k) {
                float a = fabsf(zr[k].x - zj);
                cs += a * __builtin_amdgcn_rcpf(1.f + __expf(DELTA - a)) - a * a;
            }
            sum += cs;
        }
    }

#pragma unroll
    for (int off = 32; off; off >>= 1) sum += __shfl_xor(sum, off);
    __shared__ float part[8];
    if (lane == 0) part[wv] = sum;
    __syncthreads();
    if (tid == 0) {
        float ps = 0.f;
#pragma unroll
        for (int w = 0; w < 8; ++w) ps += part[w];
        partial[b] = ps;
    }
}

__global__ __launch_bounds__(512) void k_fin(const float* __restrict__ partial,
                                             float* __restrict__ out) {
    const int tid = threadIdx.x;
    double s = 0.0;
    for (int t = tid; t < 2 * N; t += 512) s += (double)partial[t];
#pragma unroll
    for (int off = 32; off; off >>= 1) s += __shfl_xor(s, off);
    __shared__ double dp[8];
    if ((tid & 63) == 0) dp[tid >> 6] = s;
    __syncthreads();
    if (tid == 0) {
        double ds = 0.0;
#pragma unroll
        for (int w = 0; w < 8; ++w) ds += dp[w];
        const double M = (double)N * (double)NM1 * (double)NM1;
        out[0] = (float)(ds / M);
    }
}

extern "C" void kernel_launch(void* const* d_in, const int* in_sizes, int n_in,
                              void* d_out, int out_size, void* d_ws, size_t ws_size,
                              hipStream_t stream) {
    const float* feats  = (const float*)d_in[0];
    const int*   labels = (const int*)d_in[1];
    float*       out    = (float*)d_out;

    // ws layout (~2.2 MB total):
    char* ws = (char*)d_ws;
    float*          sq      = (float*)ws;                          // 1536 B
    float*          partial = (float*)(ws + 4096);                 // 3072 B
    unsigned short* Ht      = (unsigned short*)(ws + 16384);       // 768 KiB
    unsigned short* Lt      = (unsigned short*)(ws + 16384 + 786432);        // 768 KiB
    float*          z       = (float*)(ws + 16384 + 2 * 786432);   // 588 KiB

    k_cvt <<<N, 256, 0, stream>>>(feats, Ht, Lt, sq);
    k_gram<<<NTILES, 256, 0, stream>>>(Ht, Lt, sq, z);
    k_main<<<2 * N, 512, 0, stream>>>(z, labels, partial);
    k_fin <<<1, 512, 0, stream>>>(partial, out);
}

// Round 22
// 26.022 us; speedup vs baseline: 3.3369x; 1.0160x over previous
//
#include <hip/hip_runtime.h>

#define N     384
#define BSZ   192
#define NM1   383
#define D     1024
#define DELTA 0.1f
#define NT    24                    // 16-row panels / tiles per dim
#define NTILES (NT * (NT + 1) / 2)  // 300 upper-tri tiles
#define PANEL 16384                 // halfs per panel: 16 rows * 1024

typedef __attribute__((ext_vector_type(8))) short bf16x8;
typedef __attribute__((ext_vector_type(4))) float f32x4;

__device__ __forceinline__ const float* feat_row(const float* feats, int i) {
    // features laid out [192][2][1024]; logical row i of the [384,1024] concat
    int b = (i < BSZ) ? i : (i - BSZ);
    int s = (i < BSZ) ? 0 : 1;
    return feats + (size_t)(b * 2 + s) * D;
}

__device__ __forceinline__ unsigned short f2bf(float x) {  // RNE f32->bf16
    unsigned u = __builtin_bit_cast(unsigned, x);
    u = (u + 0x7FFFu + ((u >> 16) & 1u)) >> 16;
    return (unsigned short)u;
}
__device__ __forceinline__ float bf2f(unsigned short h) {
    unsigned u = ((unsigned)h) << 16;
    return __builtin_bit_cast(float, u);
}

// Fragment-major tiled index: (row, k) -> [row/16][k/8][row%16][k%8]
__device__ __forceinline__ size_t tidx(int row, int k) {
    return (size_t)(row >> 4) * PANEL + (size_t)(k >> 3) * 128
         + (size_t)(row & 15) * 8 + (k & 7);
}

// cvt, 768 blocks x 128 thr = 3 blocks/CU EXACT (R21 lesson: the 384-block
// form had the same 1.5-block/CU imbalance that cost k_main 5us). Block
// (i, hh) = row i, k-half hh. Per-half |f|^2 partial -> sqh[b]; k_gram sums.
__global__ __launch_bounds__(128) void k_cvt(const float* __restrict__ feats,
                                             unsigned short* __restrict__ Ht,
                                             unsigned short* __restrict__ Lt,
                                             float* __restrict__ sqh) {
    const int b = blockIdx.x, tid = threadIdx.x;
    const int i = b >> 1, hh = b & 1;
    __shared__ float redp[2];

    const float4 v = ((const float4*)feat_row(feats, i))[hh * 128 + tid];
    float p = 0.f;
    p = fmaf(v.x, v.x, p); p = fmaf(v.y, v.y, p);
    p = fmaf(v.z, v.z, p); p = fmaf(v.w, v.w, p);
    ushort4 h, l;
    h.x = f2bf(v.x); l.x = f2bf(v.x - bf2f(h.x));
    h.y = f2bf(v.y); l.y = f2bf(v.y - bf2f(h.y));
    h.z = f2bf(v.z); l.z = f2bf(v.z - bf2f(h.z));
    h.w = f2bf(v.w); l.w = f2bf(v.w - bf2f(h.w));
    const size_t o = tidx(i, 4 * (hh * 128 + tid));   // 8B-aligned slot
    *(ushort4*)(Ht + o) = h;
    *(ushort4*)(Lt + o) = l;

#pragma unroll
    for (int off = 32; off; off >>= 1) p += __shfl_xor(p, off);
    if ((tid & 63) == 0) redp[tid >> 6] = p;
    __syncthreads();
    if (tid == 0) sqh[b] = redp[0] + redp[1];
}

// Gram via MFMA on fragment-major H/L (structure unchanged, ~2.9us in R11);
// |f|^2 now read as sqh half-sums.
__global__ __launch_bounds__(256) void k_gram(const unsigned short* __restrict__ Ht,
                                              const unsigned short* __restrict__ Lt,
                                              const float* __restrict__ sqh,
                                              float* __restrict__ z) {
    int t = blockIdx.x, bi = 0;
    while (t >= NT - bi) { t -= NT - bi; ++bi; }
    const int bj = bi + t;
    const bool diag = (bi == bj);

    const int tid = threadIdx.x;
    const int lane = tid & 63, wv = tid >> 6;

    const size_t aBase = (size_t)bi * PANEL + (size_t)(wv * 32 + (lane >> 4)) * 128
                       + (size_t)(lane & 15) * 8;
    const size_t bBase = (size_t)bj * PANEL + (size_t)(wv * 32 + (lane >> 4)) * 128
                       + (size_t)(lane & 15) * 8;

    f32x4 aHH = {0.f,0.f,0.f,0.f}, aHL = {0.f,0.f,0.f,0.f}, aLH = {0.f,0.f,0.f,0.f};
#pragma unroll
    for (int s = 0; s < 8; ++s) {
        bf16x8 aH = *(const bf16x8*)(Ht + aBase + s * 512);
        bf16x8 aL = *(const bf16x8*)(Lt + aBase + s * 512);
        bf16x8 bH = *(const bf16x8*)(Ht + bBase + s * 512);
        bf16x8 bL = *(const bf16x8*)(Lt + bBase + s * 512);
        aHH = __builtin_amdgcn_mfma_f32_16x16x32_bf16(aH, bH, aHH, 0, 0, 0);
        aHL = __builtin_amdgcn_mfma_f32_16x16x32_bf16(aH, bL, aHL, 0, 0, 0);
        aLH = __builtin_amdgcn_mfma_f32_16x16x32_bf16(aL, bH, aLH, 0, 0, 0);
    }
    __shared__ f32x4 red[4][64];
    red[wv][lane] = aHH + aHL + aLH;
    __syncthreads();
    const int ls = tid & 63, r = tid >> 6;
    float g = red[0][ls][r] + red[1][ls][r] + red[2][ls][r] + red[3][ls][r];
    // C/D layout (verified): col = lane&15, row = (lane>>4)*4 + reg
    const int jj = bj * 16 + (ls & 15);
    const int ii = bi * 16 + ((ls >> 4) << 2) + r;
    if (ii != jj && (!diag || ii < jj)) {
        const float sqi = sqh[2 * ii] + sqh[2 * ii + 1];
        const float sqj = sqh[2 * jj] + sqh[2 * jj + 1];
        float sd = fmaxf(sqi + sqj - 2.f * g, 0.f);
        float v  = sqrtf(sd);
        z[ii * NM1 + (jj < ii ? jj : jj - 1)] = v;
        z[jj * NM1 + (ii < jj ? ii : ii - 1)] = v;
    }
}

// 768 blocks x 512 thr = 3 blocks/CU (R21, -5us). Sort streamlined: z-value
// and y-bin live in registers (1:1 tid<->element), zbuf/yrow LDS removed,
// 6 barriers -> 4. Sweep/correction identical to R21.
__global__ __launch_bounds__(512) void k_main(const float* __restrict__ z,
                                              const int* __restrict__ labels,
                                              float* __restrict__ partial) {
    const int b = blockIdx.x, tid = threadIdx.x;
    const int i = b >> 1, h = b & 1;
    const int lane = tid & 63, wv = tid >> 6;
    __shared__ int cnt[64], startv[64], cur[64];
    __shared__ float rankd[64];
    __shared__ float2 zr[N];      // sorted (z, rank*DELTA); slot 383 = (0,0)
    __shared__ unsigned grs[N];   // lo | hi<<9 per sorted slot

    if (tid < 64) cnt[tid] = 0;
    float zi = 0.f;
    int   ya = 0;
    const int li = labels[(i < BSZ) ? i : (i - BSZ)];
    if (tid < NM1) {
        zi = z[i * NM1 + tid];
        int col = tid + (tid >= i ? 1 : 0);
        ya = abs(li - labels[(col < BSZ) ? col : (col - BSZ)]);
    }
    __syncthreads();
    if (tid < NM1) atomicAdd(&cnt[ya], 1);
    __syncthreads();
    if (tid < 64) {                    // wave-0 parallel exclusive scans
        const int c  = cnt[tid];
        const int nz = (c > 0) ? 1 : 0;
        int sc = c, sn = nz;
#pragma unroll
        for (int d = 1; d < 64; d <<= 1) {
            int tc = __shfl_up(sc, d);
            int tn = __shfl_up(sn, d);
            if (tid >= d) { sc += tc; sn += tn; }
        }
        startv[tid] = sc - c;
        cur[tid]    = sc - c;
        rankd[tid]  = (float)(sn - nz) * DELTA;
    }
    if (tid == 511) { zr[NM1] = make_float2(0.f, 0.f); grs[NM1] = 0u; }
    __syncthreads();
    if (tid < NM1) {
        int pos = atomicAdd(&cur[ya], 1);
        zr[pos]  = make_float2(zi, rankd[ya]);
        grs[pos] = (unsigned)startv[ya] | ((unsigned)(startv[ya] + cnt[ya]) << 9);
    }
    __syncthreads();

    // 6 k-slots per lane: each wave covers all 384 slots (incl pad-k)
    float2 S[6];
#pragma unroll
    for (int s = 0; s < 6; ++s) S[s] = zr[lane + 64 * s];

    // 24 j per wave (subrange h*8+wv of 16); 3 batches of 8 j, 4 b128 reads
    const int j0 = (h * 8 + wv) * 24;
    float a0[6] = {0,0,0,0,0,0}, a1[6] = {0,0,0,0,0,0};
#pragma unroll
    for (int bb = 0; bb < 3; ++bb) {
        const int j = j0 + bb * 8;
        const float4 qA = *(const float4*)&zr[j];       // j even: 16B aligned
        const float4 qB = *(const float4*)&zr[j + 2];
        const float4 qC = *(const float4*)&zr[j + 4];
        const float4 qD = *(const float4*)&zr[j + 6];
#pragma unroll
        for (int s = 0; s < 6; ++s) {
            float t;
            t = fabsf(S[s].x - qA.x) - fabsf(S[s].y - qA.y); a0[s] = fmaf(t, t, a0[s]);
            t = fabsf(S[s].x - qA.z) - fabsf(S[s].y - qA.w); a1[s] = fmaf(t, t, a1[s]);
            t = fabsf(S[s].x - qB.x) - fabsf(S[s].y - qB.y); a0[s] = fmaf(t, t, a0[s]);
            t = fabsf(S[s].x - qB.z) - fabsf(S[s].y - qB.w); a1[s] = fmaf(t, t, a1[s]);
            t = fabsf(S[s].x - qC.x) - fabsf(S[s].y - qC.y); a0[s] = fmaf(t, t, a0[s]);
            t = fabsf(S[s].x - qC.z) - fabsf(S[s].y - qC.w); a1[s] = fmaf(t, t, a1[s]);
            t = fabsf(S[s].x - qD.x) - fabsf(S[s].y - qD.y); a0[s] = fmaf(t, t, a0[s]);
            t = fabsf(S[s].x - qD.z) - fabsf(S[s].y - qD.w); a1[s] = fmaf(t, t, a1[s]);
        }
    }
    float sum = 0.f;
#pragma unroll
    for (int s = 0; s < 6; ++s) sum += a0[s] + a1[s];

    // pad compensation, split per half:
    //  block h sweeps pad-k x J_h -> subtract sum_{j in J_h, j real} (zj-rj)^2
    //  block h=1 also sweeps pad-j x all k -> subtract sum_{k real} (zk-rk)^2
    {
        float comp = 0.f;
        if (h == 0) {
            if (tid < 192) { float2 e = zr[tid];       float d = e.x - e.y; comp += d * d; }
        } else {
            if (tid < 191) { float2 e = zr[192 + tid]; float d = e.x - e.y; comp += d * d; }
            if (tid < NM1) { float2 e = zr[tid];       float d = e.x - e.y; comp += d * d; }
        }
        sum -= comp;
    }

    // correction over same-y pairs, anchors split per half: h*192 + [0,192)
    {
        const int anchor = h * 192 + tid;
        if (tid < 192 && anchor < NM1) {
            const float    zj = zr[anchor].x;
            const unsigned g  = grs[anchor];
            const int lo = g & 0x1FF;
            const int hi = (g >> 9) & 0x1FF;
            float cs = 0.f;
            for (int k = lo; k < hi; ++k) {
                float a = fabsf(zr[k].x - zj);
                cs += a * __builtin_amdgcn_rcpf(1.f + __expf(DELTA - a)) - a * a;
            }
            sum += cs;
        }
    }

#pragma unroll
    for (int off = 32; off; off >>= 1) sum += __shfl_xor(sum, off);
    __shared__ float part[8];
    if (lane == 0) part[wv] = sum;
    __syncthreads();
    if (tid == 0) {
        float ps = 0.f;
#pragma unroll
        for (int w = 0; w < 8; ++w) ps += part[w];
        partial[b] = ps;
    }
}

__global__ __launch_bounds__(512) void k_fin(const float* __restrict__ partial,
                                             float* __restrict__ out) {
    const int tid = threadIdx.x;
    double s = 0.0;
    for (int t = tid; t < 2 * N; t += 512) s += (double)partial[t];
#pragma unroll
    for (int off = 32; off; off >>= 1) s += __shfl_xor(s, off);
    __shared__ double dp[8];
    if ((tid & 63) == 0) dp[tid >> 6] = s;
    __syncthreads();
    if (tid == 0) {
        double ds = 0.0;
#pragma unroll
        for (int w = 0; w < 8; ++w) ds += dp[w];
        const double M = (double)N * (double)NM1 * (double)NM1;
        out[0] = (float)(ds / M);
    }
}

extern "C" void kernel_launch(void* const* d_in, const int* in_sizes, int n_in,
                              void* d_out, int out_size, void* d_ws, size_t ws_size,
                              hipStream_t stream) {
    const float* feats  = (const float*)d_in[0];
    const int*   labels = (const int*)d_in[1];
    float*       out    = (float*)d_out;

    // ws layout (~2.2 MB total):
    char* ws = (char*)d_ws;
    float*          sqh     = (float*)ws;                          // 3072 B
    float*          partial = (float*)(ws + 4096);                 // 3072 B
    unsigned short* Ht      = (unsigned short*)(ws + 16384);       // 768 KiB
    unsigned short* Lt      = (unsigned short*)(ws + 16384 + 786432);        // 768 KiB
    float*          z       = (float*)(ws + 16384 + 2 * 786432);   // 588 KiB

    k_cvt <<<2 * N, 128, 0, stream>>>(feats, Ht, Lt, sqh);
    k_gram<<<NTILES, 256, 0, stream>>>(Ht, Lt, sqh, z);
    k_main<<<2 * N, 512, 0, stream>>>(z, labels, partial);
    k_fin <<<1, 512, 0, stream>>>(partial, out);
}